// Round 11
// baseline (1922.425 us; speedup 1.0000x reference)
//
#include <hip/hip_runtime.h>
#include <hip/hip_bf16.h>

// Shapes: B=128, L=512, D=13, H=128, G=4H=512.
typedef __attribute__((ext_vector_type(8))) short bf16x8;
typedef __attribute__((ext_vector_type(4))) float f32x4;
typedef __attribute__((ext_vector_type(2))) _Float16 f16x2;

__device__ __forceinline__ float bfbits(unsigned short u) {
  return __uint_as_float(((unsigned int)u) << 16);
}
__device__ __forceinline__ float rcpf(float x) { return __builtin_amdgcn_rcpf(x); }
__device__ __forceinline__ float sigf(float x) { return rcpf(1.f + __expf(-x)); }
__device__ __forceinline__ float tanhf_(float x) {
  x = fminf(15.f, fmaxf(-15.f, x));
  float t = __expf(2.f * x);
  return 1.f - 2.f * rcpf(t + 1.f);
}
#if __has_builtin(__builtin_amdgcn_fdot2)
__device__ __forceinline__ float FDOT2(f16x2 a, f16x2 b, float c) {
  return __builtin_amdgcn_fdot2(a, b, c, false);
}
#else
__device__ __forceinline__ float FDOT2(f16x2 a, f16x2 b, float c) {
  return c + (float)a.x * (float)b.x + (float)a.y * (float)b.y;
}
#endif
__device__ __forceinline__ f16x2 h2bc(unsigned int u) {
  return __builtin_bit_cast(f16x2, u);
}
__device__ __forceinline__ unsigned packh(float a, float b) {
  _Float16 ha = (_Float16)a, hb = (_Float16)b;
  return (unsigned)__builtin_bit_cast(unsigned short, ha) |
         ((unsigned)__builtin_bit_cast(unsigned short, hb) << 16);
}

// ---------------------------------------------------------------------------
// Weight prep: whht[lay][d][k][j] fp32 transposed; wihbf (21|31|32) bf16;
// bsum = bih + bhh.
// ---------------------------------------------------------------------------
__global__ __launch_bounds__(256) void wconv(
    const float* whh0, const float* whh1, const float* whh2, const float* whh3, const float* whh4,
    const float* wi21, const float* wi31, const float* wi32,
    const float* bi0, const float* bh0, const float* bi1, const float* bh1,
    const float* bi2, const float* bh2, const float* bi3, const float* bh3,
    const float* bi4, const float* bh4,
    float* whht, __hip_bfloat16* wihbf, float* bsum)
{
  int tid = blockIdx.x * 256 + threadIdx.x;
  if (tid < 5 * 131072) {                       // whht: [5][2][128][512]
    int lay = tid / 131072, r = tid % 131072;
    const float* src = lay == 0 ? whh0 : lay == 1 ? whh1 : lay == 2 ? whh2 : lay == 3 ? whh3 : whh4;
    int d = r >> 16;
    int k = (r >> 9) & 127;
    int j = r & 511;
    whht[tid] = src[((size_t)d * 512 + j) * 128 + k];
    return;
  }
  int t2 = tid - 5 * 131072;
  if (t2 < 1048576) {                           // wihbf: w21 | w31 | w32 (bf16)
    const float* src; int idx;
    if (t2 < 262144)      { src = wi21; idx = t2; }
    else if (t2 < 786432) { src = wi31; idx = t2 - 262144; }
    else                  { src = wi32; idx = t2 - 786432; }
    wihbf[t2] = __float2bfloat16(src[idx]);
    return;
  }
  int t3 = t2 - 1048576;
  if (t3 < 5120) {                              // bsum: [5][2][512]
    int lay = t3 >> 10, idx = t3 & 1023;
    const float* bi = lay == 0 ? bi0 : lay == 1 ? bi1 : lay == 2 ? bi2 : lay == 3 ? bi3 : bi4;
    const float* bh = lay == 0 ? bh0 : lay == 1 ? bh1 : lay == 2 ? bh2 : lay == 3 ? bh3 : bh4;
    bsum[t3] = bi[idx] + bh[idx];
  }
}

// ---------------------------------------------------------------------------
// bf16 MFMA projection GEMM (unchanged, proven).
// ---------------------------------------------------------------------------
__global__ __launch_bounds__(256) void projM(
    const __hip_bfloat16* __restrict__ A, int lda, int K,
    const __hip_bfloat16* __restrict__ Bw,
    const float* __restrict__ bsum,
    __hip_bfloat16* __restrict__ out)
{
  int d = blockIdx.z;
  const __hip_bfloat16* Bp = Bw + (size_t)d * 512 * K;
  const float* bs = bsum + d * 512;
  __hip_bfloat16* op = out + (size_t)d * 65536 * 512;
  int m0 = blockIdx.y * 128, n0 = blockIdx.x * 128;
  __shared__ __align__(16) __hip_bfloat16 As[128][32];
  __shared__ __align__(16) __hip_bfloat16 Bs[128][32];
  int tid = threadIdx.x, w = tid >> 6, l = tid & 63;
  int wm = (w >> 1) * 64, wn = (w & 1) * 64;
  f32x4 acc[4][4];
#pragma unroll
  for (int mi = 0; mi < 4; ++mi)
#pragma unroll
    for (int ni = 0; ni < 4; ++ni) acc[mi][ni] = (f32x4){0.f, 0.f, 0.f, 0.f};
  int srow = tid >> 2, sc = tid & 3;
  for (int k0 = 0; k0 < K; k0 += 32) {
#pragma unroll
    for (int p = 0; p < 2; ++p) {
      int row = p * 64 + srow;
      int slot = sc ^ (row & 3);
      uint4 va = *(const uint4*)(A + (size_t)(m0 + row) * lda + k0 + sc * 8);
      *(uint4*)(&As[row][slot * 8]) = va;
      uint4 vb = *(const uint4*)(Bp + (size_t)(n0 + row) * K + k0 + sc * 8);
      *(uint4*)(&Bs[row][slot * 8]) = vb;
    }
    __syncthreads();
    bf16x8 af[4], bfr[4];
#pragma unroll
    for (int mi = 0; mi < 4; ++mi) {
      int row = wm + mi * 16 + (l & 15);
      int slot = (l >> 4) ^ (row & 3);
      af[mi] = *(const bf16x8*)(&As[row][slot * 8]);
    }
#pragma unroll
    for (int ni = 0; ni < 4; ++ni) {
      int row = wn + ni * 16 + (l & 15);
      int slot = (l >> 4) ^ (row & 3);
      bfr[ni] = *(const bf16x8*)(&Bs[row][slot * 8]);
    }
#pragma unroll
    for (int mi = 0; mi < 4; ++mi)
#pragma unroll
      for (int ni = 0; ni < 4; ++ni)
        acc[mi][ni] = __builtin_amdgcn_mfma_f32_16x16x32_bf16(af[mi], bfr[ni], acc[mi][ni], 0, 0, 0);
    __syncthreads();
  }
#pragma unroll
  for (int ni = 0; ni < 4; ++ni) {
    int col = n0 + wn + ni * 16 + (l & 15);
    float bsv = bs[col];
#pragma unroll
    for (int mi = 0; mi < 4; ++mi) {
#pragma unroll
      for (int q = 0; q < 4; ++q) {
        int row = m0 + wm + mi * 16 + (l >> 4) * 4 + q;
        op[(size_t)row * 512 + col] = __float2bfloat16(acc[mi][ni][q] + bsv);
      }
    }
  }
}

// ---------------------------------------------------------------------------
// LSTM scan v9: scan7 dual-pipeline + vmcnt-free steady state.
//  - xg staged in LDS as double-buffered 8-step chunks (1 coalesced uint4
//    load + ds_write per thread per 8 iters); cell adds xg from LDS.
//  - y staged in LDS [16][128], flushed as coalesced dword stores 1/8 iters.
//  => 7/8 iterations have NO outstanding VMEM at the barriers (the drain
//     that previously cost ~400-500 cy per barrier).
// ---------------------------------------------------------------------------
struct ScanP {
  const __hip_bfloat16* xg;   // non-FUSE: [2][B][512][512]
  const float* wihx;          // FUSE: original Wih [2][512][13]
  const float* bs;            // FUSE: bsum for this layer [2][512]
  const float* whht;          // [2][128][512]
  __hip_bfloat16* yout; int ycols; int ycoloff;
  float* y3out; int y3off;    // maxpool mode when yout == nullptr
};

#define DOT32(W, HL, curx, S0, S1) { \
  const uint4* hb4_ = (const uint4*)&HL[curx][kq * 16]; \
  uint4 hA_ = hb4_[0], hB_ = hb4_[1]; \
  float a00_ = 0.f, a01_ = 0.f, a10_ = 0.f, a11_ = 0.f; \
  unsigned int u0_[8] = {hA_.x, hA_.y, hA_.z, hA_.w, hB_.x, hB_.y, hB_.z, hB_.w}; \
  _Pragma("unroll") \
  for (int m = 0; m < 8; m += 2) { \
    f16x2 h0_ = h2bc(u0_[m]), h1_ = h2bc(u0_[m + 1]); \
    a00_ = FDOT2(W[m], h0_, a00_);           a01_ = FDOT2(W[m + 1], h1_, a01_); \
    a10_ = FDOT2(W[16 + m], h0_, a10_);      a11_ = FDOT2(W[16 + m + 1], h1_, a11_); } \
  uint4 hC_ = hb4_[2], hD_ = hb4_[3]; \
  unsigned int u1_[8] = {hC_.x, hC_.y, hC_.z, hC_.w, hD_.x, hD_.y, hD_.z, hD_.w}; \
  _Pragma("unroll") \
  for (int m = 0; m < 8; m += 2) { \
    f16x2 h0_ = h2bc(u1_[m]), h1_ = h2bc(u1_[m + 1]); \
    a00_ = FDOT2(W[8 + m], h0_, a00_);       a01_ = FDOT2(W[8 + m + 1], h1_, a01_); \
    a10_ = FDOT2(W[24 + m], h0_, a10_);      a11_ = FDOT2(W[24 + m + 1], h1_, a11_); } \
  S0 = a00_ + a01_; S1 = a10_ + a11_; }

// Cell: gate sums from p_lds (+ xg from LDS chunk for non-FUSE), exact fp32
// c/h, h -> packed fp16 LDS, y -> LDS stage (flushed in chunks).
#define CELLPHASE(P, CT, PL, HL, CURX, TS, XS, YST) { \
  int ct_ = (CT); int ts_ = (TS); \
  float gi = PL[0][ct_] + PL[1][ct_] + PL[2][ct_] + PL[3][ct_]; \
  float gf = PL[0][ct_ + 128] + PL[1][ct_ + 128] + PL[2][ct_ + 128] + PL[3][ct_ + 128]; \
  float gg = PL[0][ct_ + 256] + PL[1][ct_ + 256] + PL[2][ct_ + 256] + PL[3][ct_ + 256]; \
  float go = PL[0][ct_ + 384] + PL[1][ct_ + 384] + PL[2][ct_ + 384] + PL[3][ct_ + 384]; \
  if (!FUSE) { \
    int bs_ = (((ts_ >> 3) & 1) * 8 + (d ? (7 - (ts_ & 7)) : (ts_ & 7))) * 512; \
    gi += bfbits(XS[bs_ + ct_]);       gf += bfbits(XS[bs_ + 128 + ct_]); \
    gg += bfbits(XS[bs_ + 256 + ct_]); go += bfbits(XS[bs_ + 384 + ct_]); \
  } \
  creg = sigf(gf) * creg + sigf(gi) * tanhf_(gg); \
  float h_ = sigf(go) * tanhf_(creg); \
  _Float16 hf_ = (_Float16)h_; \
  ((unsigned short*)&HL[CURX][0])[ct_] = __builtin_bit_cast(unsigned short, hf_); \
  if (P.yout) { \
    __hip_bfloat16 hb_ = __float2bfloat16(h_); \
    YST[(ts_ & 15) * 128 + ct_] = __builtin_bit_cast(unsigned short, hb_); \
  } else mreg = fmaxf(mreg, h_); }

// Flush one 8-step y chunk (coalesced dword stores; threads li 0..511/layer).
#define YFLUSH(FC) { \
  int fc_ = (FC); \
  if ((half == 0 && pa.yout) || (half == 1 && DUALB && pb.yout)) { \
    __hip_bfloat16* yp_ = half ? pb.yout : pa.yout; \
    int yc_ = half ? pb.ycols : pa.ycols; \
    int yo_ = half ? pb.ycoloff : pa.ycoloff; \
    const unsigned short* ys_ = half ? ystB : ystA; \
    int r_ = li >> 6, cw_ = li & 63; \
    int ts_ = fc_ * 8 + r_; \
    int tt_ = d ? 511 - ts_ : ts_; \
    unsigned v_ = *(const unsigned*)(ys_ + ((fc_ & 1) * 8 + r_) * 128 + cw_ * 2); \
    *(unsigned*)((unsigned short*)yp_ + ((size_t)b * 512 + tt_) * yc_ + yo_ + d * 128 + cw_ * 2) = v_; \
  } }

template<bool DUALB, bool FUSE>
__global__ __launch_bounds__(1024, 4) void scan9(ScanP pa, ScanP pb, const float* xin)
{
  const int b = blockIdx.x, d = blockIdx.y;
  const int tid = threadIdx.x;
  const int kq = tid >> 8, j2 = tid & 255;
  const int half = tid >> 9, li = tid & 511;
  __shared__ unsigned int hA[2][64];
  __shared__ unsigned int hB[DUALB ? 2 : 1][64];
  __shared__ float pA[4][512];
  __shared__ float pB[DUALB ? 4 : 1][512];
  __shared__ unsigned int x_lds[FUSE ? 4096 : 4];            // FUSE x rows
  __shared__ __align__(16) unsigned short xsA[FUSE ? 8 : 8192];   // [2][8][512]
  __shared__ __align__(16) unsigned short xsB[(DUALB && !FUSE) ? 8192 : 8];
  __shared__ __align__(8) unsigned short ystA[2048];              // [16][128]
  __shared__ __align__(8) unsigned short ystB[DUALB ? 2048 : 8];

  // --- recurrent weights (packed f16 pairs) --------------------------------
  f16x2 w16A[32], w16B[DUALB ? 32 : 1];
  {
    const float* wp = pa.whht + (size_t)d * 65536;
#pragma unroll
    for (int g2 = 0; g2 < 2; ++g2)
#pragma unroll
      for (int m = 0; m < 16; ++m) {
        int k = kq * 32 + 2 * m;
        int col = j2 + g2 * 256;
        f16x2 t;
        t.x = (_Float16)wp[(size_t)k * 512 + col];
        t.y = (_Float16)wp[(size_t)(k + 1) * 512 + col];
        w16A[g2 * 16 + m] = t;
      }
  }
  if (DUALB) {
    const float* wp = pb.whht + (size_t)d * 65536;
#pragma unroll
    for (int g2 = 0; g2 < 2; ++g2)
#pragma unroll
      for (int m = 0; m < 16; ++m) {
        int k = kq * 32 + 2 * m;
        int col = j2 + g2 * 256;
        f16x2 t;
        t.x = (_Float16)wp[(size_t)k * 512 + col];
        t.y = (_Float16)wp[(size_t)(k + 1) * 512 + col];
        w16B[g2 * 16 + m] = t;
      }
  }
#pragma unroll
  for (int i = 0; i < 32; ++i) asm volatile("" : "+v"(w16A[i]));
  if (DUALB) {
#pragma unroll
    for (int i = 0; i < 32; ++i) asm volatile("" : "+v"(w16B[i]));
  }

  // --- FUSE: x-projection weights + full-x staging (unchanged from R10) ----
  f16x2 wxA[4], wxB[4];
  if (FUSE) {
    int kd = kq * 4;
#pragma unroll
    for (int g2 = 0; g2 < 2; ++g2) {
      int col = j2 + g2 * 256;
#pragma unroll
      for (int p = 0; p < 2; ++p) {
        int d0 = kd + 2 * p, d1 = kd + 2 * p + 1;
        float a0 = d0 < 13 ? pa.wihx[((size_t)d * 512 + col) * 13 + d0] : (d0 == 15 ? pa.bs[d * 512 + col] : 0.f);
        float a1 = d1 < 13 ? pa.wihx[((size_t)d * 512 + col) * 13 + d1] : (d1 == 15 ? pa.bs[d * 512 + col] : 0.f);
        f16x2 ta; ta.x = (_Float16)a0; ta.y = (_Float16)a1;
        wxA[g2 * 2 + p] = ta;
        float b0 = d0 < 13 ? pb.wihx[((size_t)d * 512 + col) * 13 + d0] : (d0 == 15 ? pb.bs[d * 512 + col] : 0.f);
        float b1 = d1 < 13 ? pb.wihx[((size_t)d * 512 + col) * 13 + d1] : (d1 == 15 ? pb.bs[d * 512 + col] : 0.f);
        f16x2 tb; tb.x = (_Float16)b0; tb.y = (_Float16)b1;
        wxB[g2 * 2 + p] = tb;
      }
    }
#pragma unroll
    for (int i = 0; i < 4; ++i) { asm volatile("" : "+v"(wxA[i])); asm volatile("" : "+v"(wxB[i])); }
    for (int i = tid; i < 4096; i += 1024) {
      int t_ = i >> 3, k_ = i & 7;
      int d0 = 2 * k_, d1 = 2 * k_ + 1;
      float v0 = d0 < 13 ? xin[((size_t)b * 512 + t_) * 13 + d0] : (d0 == 15 ? 1.f : 0.f);
      float v1 = d1 < 13 ? xin[((size_t)b * 512 + t_) * 13 + d1] : (d1 == 15 ? 1.f : 0.f);
      x_lds[i] = packh(v0, v1);
    }
  }

  const unsigned short* xga = FUSE ? (const unsigned short*)0
                                   : (const unsigned short*)pa.xg + ((size_t)(d * 128 + b)) * 262144;
  const unsigned short* xgb = (DUALB && !FUSE) ? (const unsigned short*)pb.xg + ((size_t)(d * 128 + b)) * 262144
                                               : (const unsigned short*)0;

  // --- prologue: stage xg chunk 0 (steps 0..7) -----------------------------
  if (!FUSE && (half == 0 || DUALB)) {
    int gr0 = d ? 504 : 0;                      // ascending-tt rows of chunk 0
    const unsigned short* src = half ? xgb : xga;
    unsigned short* dstp = half ? xsB : xsA;
    uint4 v = *(const uint4*)(src + (size_t)gr0 * 512 + li * 8);
    *(uint4*)(dstp + li * 8) = v;
  }
  if (tid < 64) { hA[0][tid] = 0u; if (DUALB) hB[0][tid] = 0u; }
  float creg = 0.f, mreg = -1e30f;
  int curA = 0, curB = 0;
  __syncthreads();

  for (int t = 0; t < 512; ++t) {
    // chunk prefetch: issue load now, ds_write at end of beta (latency hidden)
    uint4 pref; bool dopref = false;
    if (!FUSE && (t & 7) == 0 && t + 8 < 512 && (half == 0 || DUALB)) {
      dopref = true;
      int grb = d ? (496 - t) : (t + 8);        // ascending-tt rows of chunk c+1
      const unsigned short* src = half ? xgb : xga;
      pref = *(const uint4*)(src + (size_t)grb * 512 + li * 8);
    }

    // ---------------- phase alpha: dots_A(t) || cell_B(t-1) ----------------
    {
      float s0, s1;
      DOT32(w16A, hA, curA, s0, s1);
      if (FUSE) {
        int tt = d ? 511 - t : t;
        uint2 xv = *(const uint2*)&x_lds[tt * 8 + kq * 2];
        f16x2 x0 = h2bc(xv.x), x1 = h2bc(xv.y);
        s0 = FDOT2(wxA[0], x0, s0); s0 = FDOT2(wxA[1], x1, s0);
        s1 = FDOT2(wxA[2], x0, s1); s1 = FDOT2(wxA[3], x1, s1);
      }
      pA[kq][j2] = s0;
      pA[kq][j2 + 256] = s1;
    }
    if (DUALB && t > 0 && tid >= 128 && tid < 256) {
      CELLPHASE(pb, tid - 128, pB, hB, curB ^ 1, t - 1, xsB, ystB);
    }
    if ((t & 7) == 1 && t >= 9) { YFLUSH((t >> 3) - 1); }   // flush prev chunk
    __syncthreads();
    if (DUALB && t > 0) curB ^= 1;

    // ---------------- phase beta: dots_B(t) || cell_A(t) -------------------
    if (DUALB) {
      float s0, s1;
      DOT32(w16B, hB, curB, s0, s1);
      if (FUSE) {
        int tt = d ? 511 - t : t;
        uint2 xv = *(const uint2*)&x_lds[tt * 8 + kq * 2];
        f16x2 x0 = h2bc(xv.x), x1 = h2bc(xv.y);
        s0 = FDOT2(wxB[0], x0, s0); s0 = FDOT2(wxB[1], x1, s0);
        s1 = FDOT2(wxB[2], x0, s1); s1 = FDOT2(wxB[3], x1, s1);
      }
      pB[kq][j2] = s0;
      pB[kq][j2 + 256] = s1;
    }
    if (tid < 128) {
      CELLPHASE(pa, tid, pA, hA, curA ^ 1, t, xsA, ystA);
    }
    if (dopref) {                               // lands in buf (c+1)&1; its last
      unsigned short* dstp = half ? xsB : xsA;  // old read was pre-barrier1
      *(uint4*)(dstp + ((((t >> 3) + 1) & 1) ? 4096 : 0) + li * 8) = pref;
    }
    __syncthreads();
    curA ^= 1;
  }
  // epilogue: cell_B(511), then final y chunk flush
  if (DUALB && tid >= 128 && tid < 256) {
    CELLPHASE(pb, tid - 128, pB, hB, curB ^ 1, 511, xsB, ystB);
  }
  __syncthreads();
  YFLUSH(63);
  // maxpool outputs (d*128 offset REQUIRED — R3 lesson)
  if (!pa.yout && tid < 128)
    pa.y3out[(size_t)b * 512 + pa.y3off + d * 128 + tid] = mreg;
  if (DUALB && !pb.yout && tid >= 128 && tid < 256)
    pb.y3out[(size_t)b * 512 + pb.y3off + d * 128 + (tid - 128)] = mreg;
}

// ---------------------------------------------------------------------------
// Head: y4 = selu(y3 @ l4w^T + l4b); out = sigmoid(y4 @ fcw^T + fcb).
// ---------------------------------------------------------------------------
__global__ __launch_bounds__(256) void head(
    const float* __restrict__ y3, const float* __restrict__ l4w,
    const float* __restrict__ l4b, const float* __restrict__ fcw,
    const float* __restrict__ fcb, float* __restrict__ outp)
{
  int b = blockIdx.x, t = threadIdx.x;
  __shared__ float row[512];
  __shared__ float y4[128];
  row[t] = y3[(size_t)b * 512 + t];
  row[t + 256] = y3[(size_t)b * 512 + t + 256];
  __syncthreads();
  if (t < 128) {
    float acc = l4b[t];
    const float* wr = l4w + (size_t)t * 512;
    for (int k = 0; k < 512; ++k) acc += row[k] * wr[k];
    const float scale = 1.0507009873554804934193349852946f;
    const float alpha = 1.6732632423543772848170429916717f;
    y4[t] = acc > 0.f ? scale * acc : scale * alpha * (__expf(acc) - 1.f);
  }
  __syncthreads();
  if (t < 2) {
    float acc = fcb[t];
    const float* wr = fcw + (size_t)t * 128;
    for (int k = 0; k < 128; ++k) acc += y4[k] * wr[k];
    outp[b * 2 + t] = 1.f / (1.f + __expf(-acc));
  }
}

extern "C" void kernel_launch(void* const* d_in, const int* in_sizes, int n_in,
                              void* d_out, int out_size, void* d_ws, size_t ws_size,
                              hipStream_t stream) {
  (void)in_sizes; (void)n_in; (void)out_size;
  const float* x     = (const float*)d_in[0];
  const float* Wih1  = (const float*)d_in[1];
  const float* Whh1  = (const float*)d_in[2];
  const float* bih1  = (const float*)d_in[3];
  const float* bhh1  = (const float*)d_in[4];
  const float* Wih21 = (const float*)d_in[5];
  const float* Whh21 = (const float*)d_in[6];
  const float* bih21 = (const float*)d_in[7];
  const float* bhh21 = (const float*)d_in[8];
  const float* Wih22 = (const float*)d_in[9];
  const float* Whh22 = (const float*)d_in[10];
  const float* bih22 = (const float*)d_in[11];
  const float* bhh22 = (const float*)d_in[12];
  const float* Wih31 = (const float*)d_in[13];
  const float* Whh31 = (const float*)d_in[14];
  const float* bih31 = (const float*)d_in[15];
  const float* bhh31 = (const float*)d_in[16];
  const float* Wih32 = (const float*)d_in[17];
  const float* Whh32 = (const float*)d_in[18];
  const float* bih32 = (const float*)d_in[19];
  const float* bhh32 = (const float*)d_in[20];
  const float* l4w   = (const float*)d_in[21];
  const float* l4b   = (const float*)d_in[22];
  const float* fcw   = (const float*)d_in[23];
  const float* fcb   = (const float*)d_in[24];

  char* ws = (char*)d_ws;
  const size_t NEED_F31 = 340545536ull;
  bool f31 = (ws_size >= NEED_F31);

  __hip_bfloat16 *xgA, *xgB, *y1, *y2, *wihbf;
  float *y3, *bsum, *whht;
  if (f31) {
    xgA   = (__hip_bfloat16*)(ws);
    xgB   = (__hip_bfloat16*)(ws + 134217728);
    y1    = (__hip_bfloat16*)(ws + 134217728);   // alias xgB head: dead before proj32 writes xgB
    y2    = (__hip_bfloat16*)(ws + 268435456);
    y3    = (float*)(ws + 335544320);
    wihbf = (__hip_bfloat16*)(ws + 335806464);
    bsum  = (float*)(ws + 337903616);
    whht  = (float*)(ws + 337924096);            // end 340545536
  } else {
    xgA   = (__hip_bfloat16*)(ws);
    xgB   = xgA;
    y1    = (__hip_bfloat16*)(ws + 134217728);
    y2    = (__hip_bfloat16*)(ws + 167772160);
    y3    = (float*)(ws + 234881024);
    wihbf = (__hip_bfloat16*)(ws + 235143168);
    bsum  = (float*)(ws + 237240320);
    whht  = (float*)(ws + 237260800);            // end ~239.9 MB
  }

  wconv<<<6676, 256, 0, stream>>>(Whh1, Whh21, Whh22, Whh31, Whh32,
                                  Wih21, Wih31, Wih32,
                                  bih1, bhh1, bih21, bhh21, bih22, bhh22,
                                  bih31, bhh31, bih32, bhh32,
                                  whht, wihbf, bsum);

  ScanP P1  = {nullptr, Wih1,  bsum + 0 * 1024, whht + 0 * 131072, y1, 256, 0,   nullptr, 0};
  ScanP P22 = {nullptr, Wih22, bsum + 2 * 1024, whht + 2 * 131072, y2, 512, 256, nullptr, 0};
  ScanP P21 = {xgA, nullptr, nullptr, whht + 1 * 131072, y2, 512, 0, nullptr, 0};
  ScanP P31 = {xgA, nullptr, nullptr, whht + 3 * 131072, nullptr, 0, 0, y3, 0};
  ScanP P32 = {xgB, nullptr, nullptr, whht + 4 * 131072, nullptr, 0, 0, y3, 256};

  // layers 1 || 22, input proj fused in-kernel (no xg)
  scan9<true, true><<<dim3(128, 2), 1024, 0, stream>>>(P1, P22, x);
  // layer 21
  projM<<<dim3(4, 512, 2), 256, 0, stream>>>(y1, 256, 256, wihbf + 0, bsum + 1 * 1024, xgA);
  scan9<false, false><<<dim3(128, 2), 1024, 0, stream>>>(P21, P21, nullptr);
  if (f31) {
    // layers 31 || 32 (two xg buffers)
    projM<<<dim3(4, 512, 2), 256, 0, stream>>>(y2, 512, 512, wihbf + 262144, bsum + 3 * 1024, xgA);
    projM<<<dim3(4, 512, 2), 256, 0, stream>>>(y2, 512, 256, wihbf + 786432, bsum + 4 * 1024, xgB);
    scan9<true, false><<<dim3(128, 2), 1024, 0, stream>>>(P31, P32, nullptr);
  } else {
    projM<<<dim3(4, 512, 2), 256, 0, stream>>>(y2, 512, 512, wihbf + 262144, bsum + 3 * 1024, xgA);
    scan9<false, false><<<dim3(128, 2), 1024, 0, stream>>>(P31, P31, nullptr);
    projM<<<dim3(4, 512, 2), 256, 0, stream>>>(y2, 512, 256, wihbf + 786432, bsum + 4 * 1024, xgA);
    scan9<false, false><<<dim3(128, 2), 1024, 0, stream>>>(P32, P32, nullptr);
  }
  head<<<128, 256, 0, stream>>>(y3, l4w, l4b, fcw, fcb, (float*)d_out);
}

// Round 12
// 1848.842 us; speedup vs baseline: 1.0398x; 1.0398x over previous
//
#include <hip/hip_runtime.h>
#include <hip/hip_bf16.h>

// Shapes: B=128, L=512, D=13, H=128, G=4H=512.
typedef __attribute__((ext_vector_type(8))) short bf16x8;
typedef __attribute__((ext_vector_type(4))) float f32x4;
typedef __attribute__((ext_vector_type(2))) _Float16 f16x2;

__device__ __forceinline__ float bfbits(unsigned short u) {
  return __uint_as_float(((unsigned int)u) << 16);
}
__device__ __forceinline__ float rcpf(float x) { return __builtin_amdgcn_rcpf(x); }
__device__ __forceinline__ float sigf(float x) { return rcpf(1.f + __expf(-x)); }
__device__ __forceinline__ float tanhf_(float x) {
  x = fminf(15.f, fmaxf(-15.f, x));
  float t = __expf(2.f * x);
  return 1.f - 2.f * rcpf(t + 1.f);
}
#if __has_builtin(__builtin_amdgcn_fdot2)
__device__ __forceinline__ float FDOT2(f16x2 a, f16x2 b, float c) {
  return __builtin_amdgcn_fdot2(a, b, c, false);
}
#else
__device__ __forceinline__ float FDOT2(f16x2 a, f16x2 b, float c) {
  return c + (float)a.x * (float)b.x + (float)a.y * (float)b.y;
}
#endif
__device__ __forceinline__ f16x2 h2bc(unsigned int u) {
  return __builtin_bit_cast(f16x2, u);
}
__device__ __forceinline__ unsigned packh(float a, float b) {
  _Float16 ha = (_Float16)a, hb = (_Float16)b;
  return (unsigned)__builtin_bit_cast(unsigned short, ha) |
         ((unsigned)__builtin_bit_cast(unsigned short, hb) << 16);
}

// ---------------------------------------------------------------------------
// Weight prep: wpk[lay][d][k2][512] = packed f16 {Whh[d][j][2k2], [2k2+1]}
// (transposed + packed, coalesced for the scan); wihbf (21|31|32) bf16;
// bsum = bih + bhh.
// ---------------------------------------------------------------------------
__global__ __launch_bounds__(256) void wconv(
    const float* whh0, const float* whh1, const float* whh2, const float* whh3, const float* whh4,
    const float* wi21, const float* wi31, const float* wi32,
    const float* bi0, const float* bh0, const float* bi1, const float* bh1,
    const float* bi2, const float* bh2, const float* bi3, const float* bh3,
    const float* bi4, const float* bh4,
    unsigned* wpk, __hip_bfloat16* wihbf, float* bsum)
{
  int tid = blockIdx.x * 256 + threadIdx.x;
  if (tid < 327680) {                           // wpk: [5][2][64][512]
    int lay = tid / 65536, r = tid % 65536;
    const float* src = lay == 0 ? whh0 : lay == 1 ? whh1 : lay == 2 ? whh2 : lay == 3 ? whh3 : whh4;
    int d = r >> 15;
    int k2 = (r >> 9) & 63;
    int j = r & 511;
    float v0 = src[((size_t)d * 512 + j) * 128 + 2 * k2];
    float v1 = src[((size_t)d * 512 + j) * 128 + 2 * k2 + 1];
    wpk[tid] = packh(v0, v1);
    return;
  }
  int t2 = tid - 327680;
  if (t2 < 1048576) {                           // wihbf: w21 | w31 | w32 (bf16)
    const float* src; int idx;
    if (t2 < 262144)      { src = wi21; idx = t2; }
    else if (t2 < 786432) { src = wi31; idx = t2 - 262144; }
    else                  { src = wi32; idx = t2 - 786432; }
    wihbf[t2] = __float2bfloat16(src[idx]);
    return;
  }
  int t3 = t2 - 1048576;
  if (t3 < 5120) {                              // bsum: [5][2][512]
    int lay = t3 >> 10, idx = t3 & 1023;
    const float* bi = lay == 0 ? bi0 : lay == 1 ? bi1 : lay == 2 ? bi2 : lay == 3 ? bi3 : bi4;
    const float* bh = lay == 0 ? bh0 : lay == 1 ? bh1 : lay == 2 ? bh2 : lay == 3 ? bh3 : bh4;
    bsum[t3] = bi[idx] + bh[idx];
  }
}

// ---------------------------------------------------------------------------
// bf16 MFMA projection GEMM (unchanged, proven).
// ---------------------------------------------------------------------------
__global__ __launch_bounds__(256) void projM(
    const __hip_bfloat16* __restrict__ A, int lda, int K,
    const __hip_bfloat16* __restrict__ Bw,
    const float* __restrict__ bsum,
    __hip_bfloat16* __restrict__ out)
{
  int d = blockIdx.z;
  const __hip_bfloat16* Bp = Bw + (size_t)d * 512 * K;
  const float* bs = bsum + d * 512;
  __hip_bfloat16* op = out + (size_t)d * 65536 * 512;
  int m0 = blockIdx.y * 128, n0 = blockIdx.x * 128;
  __shared__ __align__(16) __hip_bfloat16 As[128][32];
  __shared__ __align__(16) __hip_bfloat16 Bs[128][32];
  int tid = threadIdx.x, w = tid >> 6, l = tid & 63;
  int wm = (w >> 1) * 64, wn = (w & 1) * 64;
  f32x4 acc[4][4];
#pragma unroll
  for (int mi = 0; mi < 4; ++mi)
#pragma unroll
    for (int ni = 0; ni < 4; ++ni) acc[mi][ni] = (f32x4){0.f, 0.f, 0.f, 0.f};
  int srow = tid >> 2, sc = tid & 3;
  for (int k0 = 0; k0 < K; k0 += 32) {
#pragma unroll
    for (int p = 0; p < 2; ++p) {
      int row = p * 64 + srow;
      int slot = sc ^ (row & 3);
      uint4 va = *(const uint4*)(A + (size_t)(m0 + row) * lda + k0 + sc * 8);
      *(uint4*)(&As[row][slot * 8]) = va;
      uint4 vb = *(const uint4*)(Bp + (size_t)(n0 + row) * K + k0 + sc * 8);
      *(uint4*)(&Bs[row][slot * 8]) = vb;
    }
    __syncthreads();
    bf16x8 af[4], bfr[4];
#pragma unroll
    for (int mi = 0; mi < 4; ++mi) {
      int row = wm + mi * 16 + (l & 15);
      int slot = (l >> 4) ^ (row & 3);
      af[mi] = *(const bf16x8*)(&As[row][slot * 8]);
    }
#pragma unroll
    for (int ni = 0; ni < 4; ++ni) {
      int row = wn + ni * 16 + (l & 15);
      int slot = (l >> 4) ^ (row & 3);
      bfr[ni] = *(const bf16x8*)(&Bs[row][slot * 8]);
    }
#pragma unroll
    for (int mi = 0; mi < 4; ++mi)
#pragma unroll
      for (int ni = 0; ni < 4; ++ni)
        acc[mi][ni] = __builtin_amdgcn_mfma_f32_16x16x32_bf16(af[mi], bfr[ni], acc[mi][ni], 0, 0, 0);
    __syncthreads();
  }
#pragma unroll
  for (int ni = 0; ni < 4; ++ni) {
    int col = n0 + wn + ni * 16 + (l & 15);
    float bsv = bs[col];
#pragma unroll
    for (int mi = 0; mi < 4; ++mi) {
#pragma unroll
      for (int q = 0; q < 4; ++q) {
        int row = m0 + wm + mi * 16 + (l >> 4) * 4 + q;
        op[(size_t)row * 512 + col] = __float2bfloat16(acc[mi][ni][q] + bsv);
      }
    }
  }
}

// ---------------------------------------------------------------------------
// LSTM scan v10 = R10's proven dual-pipeline + packed-weight loads +
// cell-issued-before-dots in each phase (critical waves start the serial
// cell chain first; independent dot stream fills its latency).
// ---------------------------------------------------------------------------
struct ScanP {
  const __hip_bfloat16* xg;   // non-FUSE: [2][B][512][512]
  const float* wihx;          // FUSE: original Wih [2][512][13]
  const float* bs;            // FUSE: bsum for this layer [2][512]
  const unsigned* wpk;        // [2][64][512] packed f16-pair weights
  __hip_bfloat16* yout; int ycols; int ycoloff;
  float* y3out; int y3off;    // maxpool mode when yout == nullptr
};

#define DOT32(W, HL, curx, S0, S1) { \
  const uint4* hb4_ = (const uint4*)&HL[curx][kq * 16]; \
  uint4 hA_ = hb4_[0], hB_ = hb4_[1]; \
  float a00_ = 0.f, a01_ = 0.f, a10_ = 0.f, a11_ = 0.f; \
  unsigned int u0_[8] = {hA_.x, hA_.y, hA_.z, hA_.w, hB_.x, hB_.y, hB_.z, hB_.w}; \
  _Pragma("unroll") \
  for (int m = 0; m < 8; m += 2) { \
    f16x2 h0_ = h2bc(u0_[m]), h1_ = h2bc(u0_[m + 1]); \
    a00_ = FDOT2(W[m], h0_, a00_);           a01_ = FDOT2(W[m + 1], h1_, a01_); \
    a10_ = FDOT2(W[16 + m], h0_, a10_);      a11_ = FDOT2(W[16 + m + 1], h1_, a11_); } \
  uint4 hC_ = hb4_[2], hD_ = hb4_[3]; \
  unsigned int u1_[8] = {hC_.x, hC_.y, hC_.z, hC_.w, hD_.x, hD_.y, hD_.z, hD_.w}; \
  _Pragma("unroll") \
  for (int m = 0; m < 8; m += 2) { \
    f16x2 h0_ = h2bc(u1_[m]), h1_ = h2bc(u1_[m + 1]); \
    a00_ = FDOT2(W[8 + m], h0_, a00_);       a01_ = FDOT2(W[8 + m + 1], h1_, a01_); \
    a10_ = FDOT2(W[24 + m], h0_, a10_);      a11_ = FDOT2(W[24 + m + 1], h1_, a11_); } \
  S0 = a00_ + a01_; S1 = a10_ + a11_; }

#define CELLPHASE(P, CT, PL, HL, CURX, TROW) { \
  int ct_ = (CT); \
  float gi = PL[0][ct_] + PL[1][ct_] + PL[2][ct_] + PL[3][ct_]; \
  float gf = PL[0][ct_ + 128] + PL[1][ct_ + 128] + PL[2][ct_ + 128] + PL[3][ct_ + 128]; \
  float gg = PL[0][ct_ + 256] + PL[1][ct_ + 256] + PL[2][ct_ + 256] + PL[3][ct_ + 256]; \
  float go = PL[0][ct_ + 384] + PL[1][ct_ + 384] + PL[2][ct_ + 384] + PL[3][ct_ + 384]; \
  creg = sigf(gf) * creg + sigf(gi) * tanhf_(gg); \
  float h_ = sigf(go) * tanhf_(creg); \
  _Float16 hf_ = (_Float16)h_; \
  ((unsigned short*)&HL[CURX][0])[ct_] = __builtin_bit_cast(unsigned short, hf_); \
  if (P.yout) P.yout[((size_t)b * 512 + (TROW)) * P.ycols + P.ycoloff + d * 128 + ct_] = __float2bfloat16(h_); \
  else mreg = fmaxf(mreg, h_); }

template<bool DUALB, bool FUSE>
__global__ __launch_bounds__(1024, 4) void scan10(ScanP pa, ScanP pb, const float* xin)
{
  const int b = blockIdx.x, d = blockIdx.y;
  const int tid = threadIdx.x;
  const int kq = tid >> 8, j2 = tid & 255;
  __shared__ unsigned int hA[2][64];
  __shared__ unsigned int hB[DUALB ? 2 : 1][64];
  __shared__ float pA[4][512];
  __shared__ float pB[DUALB ? 4 : 1][512];
  __shared__ unsigned int x_lds[FUSE ? 4096 : 4];   // [t][8] packed f16 pairs (16 dims)

  // --- recurrent weights: coalesced packed-f16 loads (32/thread/layer) -----
  f16x2 w16A[32], w16B[DUALB ? 32 : 1];
  {
    const unsigned* wp = pa.wpk + (size_t)d * 32768;
#pragma unroll
    for (int g2 = 0; g2 < 2; ++g2)
#pragma unroll
      for (int m = 0; m < 16; ++m)
        w16A[g2 * 16 + m] = h2bc(wp[(kq * 16 + m) * 512 + j2 + g2 * 256]);
  }
  if (DUALB) {
    const unsigned* wp = pb.wpk + (size_t)d * 32768;
#pragma unroll
    for (int g2 = 0; g2 < 2; ++g2)
#pragma unroll
      for (int m = 0; m < 16; ++m)
        w16B[g2 * 16 + m] = h2bc(wp[(kq * 16 + m) * 512 + j2 + g2 * 256]);
  }
#pragma unroll
  for (int i = 0; i < 32; ++i) asm volatile("" : "+v"(w16A[i]));
  if (DUALB) {
#pragma unroll
    for (int i = 0; i < 32; ++i) asm volatile("" : "+v"(w16B[i]));
  }

  // --- FUSE: x-projection weights, dims padded to 16; dim15 = bias, x15=1 --
  f16x2 wxA[4], wxB[4];
  if (FUSE) {
    int kd = kq * 4;
#pragma unroll
    for (int g2 = 0; g2 < 2; ++g2) {
      int col = j2 + g2 * 256;
#pragma unroll
      for (int p = 0; p < 2; ++p) {
        int d0 = kd + 2 * p, d1 = kd + 2 * p + 1;
        float a0 = d0 < 13 ? pa.wihx[((size_t)d * 512 + col) * 13 + d0] : (d0 == 15 ? pa.bs[d * 512 + col] : 0.f);
        float a1 = d1 < 13 ? pa.wihx[((size_t)d * 512 + col) * 13 + d1] : (d1 == 15 ? pa.bs[d * 512 + col] : 0.f);
        f16x2 ta; ta.x = (_Float16)a0; ta.y = (_Float16)a1;
        wxA[g2 * 2 + p] = ta;
        float b0 = d0 < 13 ? pb.wihx[((size_t)d * 512 + col) * 13 + d0] : (d0 == 15 ? pb.bs[d * 512 + col] : 0.f);
        float b1 = d1 < 13 ? pb.wihx[((size_t)d * 512 + col) * 13 + d1] : (d1 == 15 ? pb.bs[d * 512 + col] : 0.f);
        f16x2 tb; tb.x = (_Float16)b0; tb.y = (_Float16)b1;
        wxB[g2 * 2 + p] = tb;
      }
    }
#pragma unroll
    for (int i = 0; i < 4; ++i) { asm volatile("" : "+v"(wxA[i])); asm volatile("" : "+v"(wxB[i])); }
    // stage x rows (packed f16, 16 dims: 13 real, 2 zero, x15=1 for bias)
    for (int i = tid; i < 4096; i += 1024) {
      int t_ = i >> 3, k_ = i & 7;
      int d0 = 2 * k_, d1 = 2 * k_ + 1;
      float v0 = d0 < 13 ? xin[((size_t)b * 512 + t_) * 13 + d0] : (d0 == 15 ? 1.f : 0.f);
      float v1 = d1 < 13 ? xin[((size_t)b * 512 + t_) * 13 + d1] : (d1 == 15 ? 1.f : 0.f);
      x_lds[i] = packh(v0, v1);
    }
  }

  const unsigned short* xga = FUSE ? (const unsigned short*)0
                                   : (const unsigned short*)pa.xg + ((size_t)(d * 128 + b)) * 262144;
  const unsigned short* xgb = (DUALB && !FUSE) ? (const unsigned short*)pb.xg + ((size_t)(d * 128 + b)) * 262144
                                               : (const unsigned short*)0;

  if (tid < 64) { hA[0][tid] = 0u; if (DUALB) hB[0][tid] = 0u; }
  float creg = 0.f, mreg = -1e30f;   // tid<128: layer A state; tid in [128,256): layer B
  int curA = 0, curB = 0;
  int tt0 = d ? 511 : 0;
  unsigned short pfa0 = 0, pfa1 = 0, pfb0 = 0, pfb1 = 0;
  if (!FUSE && kq == 0) {
    pfa0 = xga[(size_t)tt0 * 512 + j2];
    pfa1 = xga[(size_t)tt0 * 512 + j2 + 256];
    if (DUALB) {
      pfb0 = xgb[(size_t)tt0 * 512 + j2];
      pfb1 = xgb[(size_t)tt0 * 512 + j2 + 256];
    }
  }
  __syncthreads();

  for (int t = 0; t < 512; ++t) {
    int tt = d ? 511 - t : t;
    int tn = (t + 1 < 512) ? t + 1 : 511;
    int ttn = d ? 511 - tn : tn;

    // ---------------- phase alpha: cell_B(t-1) || dots_A(t) ----------------
    unsigned short pna0 = 0, pna1 = 0;
    if (!FUSE && kq == 0) {
      pna0 = xga[(size_t)ttn * 512 + j2];
      pna1 = xga[(size_t)ttn * 512 + j2 + 256];
    }
    if (DUALB && t > 0 && tid >= 128 && tid < 256) {     // cell first
      int ttpB = d ? 512 - t : t - 1;
      CELLPHASE(pb, tid - 128, pB, hB, curB ^ 1, ttpB);
    }
    {
      float s0, s1;
      DOT32(w16A, hA, curA, s0, s1);
      if (FUSE) {
        uint2 xv = *(const uint2*)&x_lds[tt * 8 + kq * 2];
        f16x2 x0 = h2bc(xv.x), x1 = h2bc(xv.y);
        s0 = FDOT2(wxA[0], x0, s0); s0 = FDOT2(wxA[1], x1, s0);
        s1 = FDOT2(wxA[2], x0, s1); s1 = FDOT2(wxA[3], x1, s1);
      } else if (kq == 0) {
        s0 += bfbits(pfa0); s1 += bfbits(pfa1);
      }
      pA[kq][j2] = s0;
      pA[kq][j2 + 256] = s1;
    }
    __syncthreads();
    if (DUALB && t > 0) curB ^= 1;

    // ---------------- phase beta: cell_A(t) || dots_B(t) -------------------
    unsigned short pnb0 = 0, pnb1 = 0;
    if (tid < 128) {                                     // cell first
      CELLPHASE(pa, tid, pA, hA, curA ^ 1, tt);
    }
    if (DUALB) {
      if (!FUSE && kq == 0) {
        pnb0 = xgb[(size_t)ttn * 512 + j2];
        pnb1 = xgb[(size_t)ttn * 512 + j2 + 256];
      }
      float s0, s1;
      DOT32(w16B, hB, curB, s0, s1);
      if (FUSE) {
        uint2 xv = *(const uint2*)&x_lds[tt * 8 + kq * 2];
        f16x2 x0 = h2bc(xv.x), x1 = h2bc(xv.y);
        s0 = FDOT2(wxB[0], x0, s0); s0 = FDOT2(wxB[1], x1, s0);
        s1 = FDOT2(wxB[2], x0, s1); s1 = FDOT2(wxB[3], x1, s1);
      } else if (kq == 0) {
        s0 += bfbits(pfb0); s1 += bfbits(pfb1);
      }
      pB[kq][j2] = s0;
      pB[kq][j2 + 256] = s1;
    }
    __syncthreads();
    curA ^= 1;
    pfa0 = pna0; pfa1 = pna1; pfb0 = pnb0; pfb1 = pnb1;
  }
  // epilogue: cell_B(511)
  if (DUALB && tid >= 128 && tid < 256) {
    int ttpB = d ? 0 : 511;
    CELLPHASE(pb, tid - 128, pB, hB, curB ^ 1, ttpB);
  }
  // maxpool outputs (d*128 offset REQUIRED — R3 lesson)
  if (!pa.yout && tid < 128)
    pa.y3out[(size_t)b * 512 + pa.y3off + d * 128 + tid] = mreg;
  if (DUALB && !pb.yout && tid >= 128 && tid < 256)
    pb.y3out[(size_t)b * 512 + pb.y3off + d * 128 + (tid - 128)] = mreg;
}

// ---------------------------------------------------------------------------
// Head: y4 = selu(y3 @ l4w^T + l4b); out = sigmoid(y4 @ fcw^T + fcb).
// ---------------------------------------------------------------------------
__global__ __launch_bounds__(256) void head(
    const float* __restrict__ y3, const float* __restrict__ l4w,
    const float* __restrict__ l4b, const float* __restrict__ fcw,
    const float* __restrict__ fcb, float* __restrict__ outp)
{
  int b = blockIdx.x, t = threadIdx.x;
  __shared__ float row[512];
  __shared__ float y4[128];
  row[t] = y3[(size_t)b * 512 + t];
  row[t + 256] = y3[(size_t)b * 512 + t + 256];
  __syncthreads();
  if (t < 128) {
    float acc = l4b[t];
    const float* wr = l4w + (size_t)t * 512;
    for (int k = 0; k < 512; ++k) acc += row[k] * wr[k];
    const float scale = 1.0507009873554804934193349852946f;
    const float alpha = 1.6732632423543772848170429916717f;
    y4[t] = acc > 0.f ? scale * acc : scale * alpha * (__expf(acc) - 1.f);
  }
  __syncthreads();
  if (t < 2) {
    float acc = fcb[t];
    const float* wr = fcw + (size_t)t * 128;
    for (int k = 0; k < 128; ++k) acc += y4[k] * wr[k];
    outp[b * 2 + t] = 1.f / (1.f + __expf(-acc));
  }
}

extern "C" void kernel_launch(void* const* d_in, const int* in_sizes, int n_in,
                              void* d_out, int out_size, void* d_ws, size_t ws_size,
                              hipStream_t stream) {
  (void)in_sizes; (void)n_in; (void)out_size;
  const float* x     = (const float*)d_in[0];
  const float* Wih1  = (const float*)d_in[1];
  const float* Whh1  = (const float*)d_in[2];
  const float* bih1  = (const float*)d_in[3];
  const float* bhh1  = (const float*)d_in[4];
  const float* Wih21 = (const float*)d_in[5];
  const float* Whh21 = (const float*)d_in[6];
  const float* bih21 = (const float*)d_in[7];
  const float* bhh21 = (const float*)d_in[8];
  const float* Wih22 = (const float*)d_in[9];
  const float* Whh22 = (const float*)d_in[10];
  const float* bih22 = (const float*)d_in[11];
  const float* bhh22 = (const float*)d_in[12];
  const float* Wih31 = (const float*)d_in[13];
  const float* Whh31 = (const float*)d_in[14];
  const float* bih31 = (const float*)d_in[15];
  const float* bhh31 = (const float*)d_in[16];
  const float* Wih32 = (const float*)d_in[17];
  const float* Whh32 = (const float*)d_in[18];
  const float* bih32 = (const float*)d_in[19];
  const float* bhh32 = (const float*)d_in[20];
  const float* l4w   = (const float*)d_in[21];
  const float* l4b   = (const float*)d_in[22];
  const float* fcw   = (const float*)d_in[23];
  const float* fcb   = (const float*)d_in[24];

  char* ws = (char*)d_ws;
  const size_t NEED_F31 = 339234816ull;
  bool f31 = (ws_size >= NEED_F31);

  __hip_bfloat16 *xgA, *xgB, *y1, *y2, *wihbf;
  float *y3, *bsum;
  unsigned *wpk;
  if (f31) {
    xgA   = (__hip_bfloat16*)(ws);
    xgB   = (__hip_bfloat16*)(ws + 134217728);
    y1    = (__hip_bfloat16*)(ws + 134217728);   // alias xgB head: dead before proj32 writes xgB
    y2    = (__hip_bfloat16*)(ws + 268435456);
    y3    = (float*)(ws + 335544320);
    wihbf = (__hip_bfloat16*)(ws + 335806464);
    bsum  = (float*)(ws + 337903616);
    wpk   = (unsigned*)(ws + 337924096);         // 1310720 B -> end 339234816
  } else {
    xgA   = (__hip_bfloat16*)(ws);
    xgB   = xgA;
    y1    = (__hip_bfloat16*)(ws + 134217728);
    y2    = (__hip_bfloat16*)(ws + 167772160);
    y3    = (float*)(ws + 234881024);
    wihbf = (__hip_bfloat16*)(ws + 235143168);
    bsum  = (float*)(ws + 237240320);
    wpk   = (unsigned*)(ws + 237260800);         // end 238571520
  }

  wconv<<<5396, 256, 0, stream>>>(Whh1, Whh21, Whh22, Whh31, Whh32,
                                  Wih21, Wih31, Wih32,
                                  bih1, bhh1, bih21, bhh21, bih22, bhh22,
                                  bih31, bhh31, bih32, bhh32,
                                  wpk, wihbf, bsum);

  ScanP P1  = {nullptr, Wih1,  bsum + 0 * 1024, wpk + 0 * 65536, y1, 256, 0,   nullptr, 0};
  ScanP P22 = {nullptr, Wih22, bsum + 2 * 1024, wpk + 2 * 65536, y2, 512, 256, nullptr, 0};
  ScanP P21 = {xgA, nullptr, nullptr, wpk + 1 * 65536, y2, 512, 0, nullptr, 0};
  ScanP P31 = {xgA, nullptr, nullptr, wpk + 3 * 65536, nullptr, 0, 0, y3, 0};
  ScanP P32 = {xgB, nullptr, nullptr, wpk + 4 * 65536, nullptr, 0, 0, y3, 256};

  // layers 1 || 22, input proj fused in-kernel (no xg)
  scan10<true, true><<<dim3(128, 2), 1024, 0, stream>>>(P1, P22, x);
  // layer 21
  projM<<<dim3(4, 512, 2), 256, 0, stream>>>(y1, 256, 256, wihbf + 0, bsum + 1 * 1024, xgA);
  scan10<false, false><<<dim3(128, 2), 1024, 0, stream>>>(P21, P21, nullptr);
  if (f31) {
    // layers 31 || 32 (two xg buffers)
    projM<<<dim3(4, 512, 2), 256, 0, stream>>>(y2, 512, 512, wihbf + 262144, bsum + 3 * 1024, xgA);
    projM<<<dim3(4, 512, 2), 256, 0, stream>>>(y2, 512, 256, wihbf + 786432, bsum + 4 * 1024, xgB);
    scan10<true, false><<<dim3(128, 2), 1024, 0, stream>>>(P31, P32, nullptr);
  } else {
    projM<<<dim3(4, 512, 2), 256, 0, stream>>>(y2, 512, 512, wihbf + 262144, bsum + 3 * 1024, xgA);
    scan10<false, false><<<dim3(128, 2), 1024, 0, stream>>>(P31, P31, nullptr);
    projM<<<dim3(4, 512, 2), 256, 0, stream>>>(y2, 512, 256, wihbf + 786432, bsum + 4 * 1024, xgA);
    scan10<false, false><<<dim3(128, 2), 1024, 0, stream>>>(P32, P32, nullptr);
  }
  head<<<128, 256, 0, stream>>>(y3, l4w, l4b, fcw, fcb, (float*)d_out);
}